// Round 3
// baseline (185.188 us; speedup 1.0000x reference)
//
#include <hip/hip_runtime.h>

// Problem constants (from reference):
//   OUT=8192, GROUPS=64, GROUP_SIZE=128 -> weight flat: 8192*64*64 int32 (each
//   holds one byte = two int4 nibbles), scale flat: 8192*64 f32, out: 8192*8192 f32.
#define NW_TOTAL 33554432u         // 8192*64*64 packed int32 elements
#define N_OCT    (NW_TOTAL / 8u)   // 4194304 chunks of 8 packed ints

// Native clang vectors (required by __builtin_nontemporal_*; HIP_vector_type is a class).
typedef int   iv4 __attribute__((ext_vector_type(4)));
typedef float fv4 __attribute__((ext_vector_type(4)));

__global__ __launch_bounds__(256)
void PackedINTSymmetricWeightsDecompressor_74440373174409_kernel(
        const int* __restrict__ w,
        const float* __restrict__ s,
        float* __restrict__ out)
{
    const unsigned stride = gridDim.x * blockDim.x;
    for (unsigned t = blockIdx.x * blockDim.x + threadIdx.x;
         t < N_OCT; t += stride) {
        // 8 packed int32 per thread-iter = 32 B read, 16 floats = 64 B write.
        const iv4* wp = reinterpret_cast<const iv4*>(w) + (size_t)t * 2;
        const iv4 w0 = __builtin_nontemporal_load(wp);
        const iv4 w1 = __builtin_nontemporal_load(wp + 1);
        // 8 ints starting at t*8 never cross a 64-int group boundary.
        const float sc = s[t >> 3];

        fv4 o0, o1, o2, o3;
        o0.x = (float)(( w0.x       & 0xF) - 8) * sc;
        o0.y = (float)(((w0.x >> 4) & 0xF) - 8) * sc;
        o0.z = (float)(( w0.y       & 0xF) - 8) * sc;
        o0.w = (float)(((w0.y >> 4) & 0xF) - 8) * sc;
        o1.x = (float)(( w0.z       & 0xF) - 8) * sc;
        o1.y = (float)(((w0.z >> 4) & 0xF) - 8) * sc;
        o1.z = (float)(( w0.w       & 0xF) - 8) * sc;
        o1.w = (float)(((w0.w >> 4) & 0xF) - 8) * sc;
        o2.x = (float)(( w1.x       & 0xF) - 8) * sc;
        o2.y = (float)(((w1.x >> 4) & 0xF) - 8) * sc;
        o2.z = (float)(( w1.y       & 0xF) - 8) * sc;
        o2.w = (float)(((w1.y >> 4) & 0xF) - 8) * sc;
        o3.x = (float)(( w1.z       & 0xF) - 8) * sc;
        o3.y = (float)(((w1.z >> 4) & 0xF) - 8) * sc;
        o3.z = (float)(( w1.w       & 0xF) - 8) * sc;
        o3.w = (float)(((w1.w >> 4) & 0xF) - 8) * sc;

        fv4* op = reinterpret_cast<fv4*>(out) + (size_t)t * 4;
        __builtin_nontemporal_store(o0, op + 0);
        __builtin_nontemporal_store(o1, op + 1);
        __builtin_nontemporal_store(o2, op + 2);
        __builtin_nontemporal_store(o3, op + 3);
    }
}

extern "C" void kernel_launch(void* const* d_in, const int* in_sizes, int n_in,
                              void* d_out, int out_size, void* d_ws, size_t ws_size,
                              hipStream_t stream) {
    const int*   w   = (const int*)d_in[0];
    const float* s   = (const float*)d_in[1];
    float*       out = (float*)d_out;

    // Memory-bound: ~2048 blocks, grid-stride (8 iters/thread at 32B/64B per iter).
    const int block = 256;
    const int grid  = 2048;
    PackedINTSymmetricWeightsDecompressor_74440373174409_kernel<<<grid, block, 0, stream>>>(w, s, out);
}

// Round 4
// 83.779 us; speedup vs baseline: 2.2104x; 2.2104x over previous
//
#include <hip/hip_runtime.h>

// Problem constants (from reference):
//   OUT=8192, GROUPS=64, GROUP_SIZE=128 -> weight flat: 8192*64*64 int32 (each
//   holds one byte = two int4 nibbles), scale flat: 8192*64 f32, out: 8192*8192 f32.
#define NW_TOTAL 33554432u          // packed int32 elements
#define N_PAIRS  (NW_TOTAL / 2u)    // 16777216 chunks of 2 packed ints

typedef int   iv2 __attribute__((ext_vector_type(2)));
typedef float fv4 __attribute__((ext_vector_type(4)));

__global__ __launch_bounds__(256)
void PackedINTSymmetricWeightsDecompressor_74440373174409_kernel(
        const int* __restrict__ w,
        const float* __restrict__ s,
        float* __restrict__ out)
{
    const unsigned stride = gridDim.x * blockDim.x;
    for (unsigned t = blockIdx.x * blockDim.x + threadIdx.x;
         t < N_PAIRS; t += stride) {
        // 2 packed int32 per thread-iter = 8 B read (contiguous 512 B/wave-instr),
        // 4 floats = 16 B write (contiguous 1 KiB/wave-instr).
        const iv2 wv = *(reinterpret_cast<const iv2*>(w) + t);
        // 2 ints starting at t*2 never cross a 64-int group boundary.
        const float sc = s[t >> 5];

        fv4 o;
        o.x = (float)(( wv.x       & 0xF) - 8) * sc;
        o.y = (float)(((wv.x >> 4) & 0xF) - 8) * sc;
        o.z = (float)(( wv.y       & 0xF) - 8) * sc;
        o.w = (float)(((wv.y >> 4) & 0xF) - 8) * sc;

        *(reinterpret_cast<fv4*>(out) + t) = o;
    }
}

extern "C" void kernel_launch(void* const* d_in, const int* in_sizes, int n_in,
                              void* d_out, int out_size, void* d_ws, size_t ws_size,
                              hipStream_t stream) {
    const int*   w   = (const int*)d_in[0];
    const float* s   = (const float*)d_in[1];
    float*       out = (float*)d_out;

    // Memory-bound: 2048 blocks (max resident), grid-stride (32 iters/thread).
    const int block = 256;
    const int grid  = 2048;
    PackedINTSymmetricWeightsDecompressor_74440373174409_kernel<<<grid, block, 0, stream>>>(w, s, out);
}

// Round 5
// 70.563 us; speedup vs baseline: 2.6245x; 1.1873x over previous
//
#include <hip/hip_runtime.h>

// Problem constants (from reference):
//   OUT=8192, GROUPS=64, GROUP_SIZE=128 -> weight flat: 8192*64*64 int32 (each
//   holds one byte = two int4 nibbles), scale flat: 8192*64 f32, out: 8192*8192 f32.
#define NW_TOTAL 33554432u          // packed int32 elements
#define N_PAIRS  (NW_TOTAL / 2u)    // 16777216 chunks of 2 packed ints

typedef int   iv2 __attribute__((ext_vector_type(2)));
typedef float fv4 __attribute__((ext_vector_type(4)));

__global__ __launch_bounds__(256)
void PackedINTSymmetricWeightsDecompressor_74440373174409_kernel(
        const int* __restrict__ w,
        const float* __restrict__ s,
        float* __restrict__ out)
{
    const unsigned stride = gridDim.x * blockDim.x;
    for (unsigned t = blockIdx.x * blockDim.x + threadIdx.x;
         t < N_PAIRS; t += stride) {
        // 2 packed int32 per thread-iter = 8 B read (contiguous 512 B/wave-instr),
        // 4 floats = 16 B write (contiguous 1 KiB/wave-instr).
        // Loads stay CACHED so the 134 MB weight allocates in L3 and survives
        // across graph replays.
        const iv2 wv = *(reinterpret_cast<const iv2*>(w) + t);
        // 2 ints starting at t*2 never cross a 64-int group boundary.
        const float sc = s[t >> 5];

        fv4 o;
        o.x = (float)(( wv.x       & 0xF) - 8) * sc;
        o.y = (float)(((wv.x >> 4) & 0xF) - 8) * sc;
        o.z = (float)(( wv.y       & 0xF) - 8) * sc;
        o.w = (float)(((wv.y >> 4) & 0xF) - 8) * sc;

        // Non-temporal STORE: output is written once, never read — skip L3
        // allocation so it doesn't evict the weight stream. Store pattern is
        // wave-contiguous (16 full 64B lines per instruction), so nt cannot
        // create partial-line write amplification (unlike round 3's gapped nt).
        __builtin_nontemporal_store(o, reinterpret_cast<fv4*>(out) + t);
    }
}

extern "C" void kernel_launch(void* const* d_in, const int* in_sizes, int n_in,
                              void* d_out, int out_size, void* d_ws, size_t ws_size,
                              hipStream_t stream) {
    const int*   w   = (const int*)d_in[0];
    const float* s   = (const float*)d_in[1];
    float*       out = (float*)d_out;

    // Memory-bound: 2048 blocks (max resident), grid-stride (32 iters/thread).
    const int block = 256;
    const int grid  = 2048;
    PackedINTSymmetricWeightsDecompressor_74440373174409_kernel<<<grid, block, 0, stream>>>(w, s, out);
}